// Round 7
// baseline (631.302 us; speedup 1.0000x reference)
//
#include <hip/hip_runtime.h>
#include <math.h>

#define D 256
#define SEGS 64
#define RPB 512      // rows per block
#define THREADS 256  // 4 waves; each wave streams RPB/4 = 128 contiguous rows
#define RPW (RPB / 4)

typedef float f32x4 __attribute__((ext_vector_type(4)));

// ---- ordered-uint encoding for float atomicMax ----
// key(f) monotone in f; key >= 0x007FFFFF for all finite floats,
// so the zero-initialized key acts as a -inf identity.
__device__ __forceinline__ unsigned enc_f32(float f) {
  unsigned u = __float_as_uint(f);
  return (u & 0x80000000u) ? ~u : (u | 0x80000000u);
}
__device__ __forceinline__ float dec_f32(unsigned k) {
  unsigned u = (k & 0x80000000u) ? (k ^ 0x80000000u) : ~k;
  return __uint_as_float(u);
}

// Single fused kernel: stream + accumulate + (last block) finalize.
// ws layout (zeroed by hipMemsetAsync before launch):
//   sums[SEGS*D] f32, maxk[SEGS*D] u32, counts[SEGS] i32, done u32.
__global__ __launch_bounds__(THREADS, 4)
void fused_kernel(const float* __restrict__ feat, const int* __restrict__ idx,
                  float* __restrict__ sums, unsigned* __restrict__ maxk,
                  int* __restrict__ counts, unsigned* __restrict__ done,
                  float* __restrict__ out, int n, int nblocks) {
  __shared__ int s_idx[RPB];
  __shared__ unsigned s_ticket;

  // idx width (int32 vs int64 little-endian): sorted data's last int32 word
  // is 63 (int32) or the 0 high-word of the last int64 element.
  const int stride = (idx[(size_t)n - 1] == 0) ? 2 : 1;
  const int r0 = blockIdx.x * RPB;
  const int rows = min(RPB, n - r0);

  for (int t = threadIdx.x; t < rows; t += THREADS)
    s_idx[t] = idx[(size_t)(r0 + t) * stride];
  __syncthreads();

  const int lane = threadIdx.x & 63;
  const int wave = threadIdx.x >> 6;
  int i = wave * RPW;
  const int re = min(i + RPW, rows);
  const float* base = feat + (size_t)r0 * D + lane * 4;

  if (i < re) {
    const int last = s_idx[re - 1];
    while (i < re) {
      const int cur = s_idx[i];
      int j;
      if (cur == last) {
        j = re;                       // fast path: run extends to range end
      } else {
        j = i + 1;                    // rare: boundary waves only
        while (s_idx[j] == cur) ++j;  // bounded: s_idx[re-1] != cur
      }

      f32x4 sum = {0.f, 0.f, 0.f, 0.f};
      f32x4 mx  = {-INFINITY, -INFINITY, -INFINITY, -INFINITY};
#pragma unroll 8
      for (int k = i; k < j; ++k) {
        const f32x4 v = __builtin_nontemporal_load(
            reinterpret_cast<const f32x4*>(base + (size_t)k * D));
        sum += v;
        mx.x = __builtin_fmaxf(mx.x, v.x);
        mx.y = __builtin_fmaxf(mx.y, v.y);
        mx.z = __builtin_fmaxf(mx.z, v.z);
        mx.w = __builtin_fmaxf(mx.w, v.w);
      }

      float* sp = sums + cur * D + lane * 4;
      atomicAdd(sp + 0, sum.x); atomicAdd(sp + 1, sum.y);
      atomicAdd(sp + 2, sum.z); atomicAdd(sp + 3, sum.w);
      unsigned* mp = maxk + cur * D + lane * 4;
      atomicMax(mp + 0, enc_f32(mx.x)); atomicMax(mp + 1, enc_f32(mx.y));
      atomicMax(mp + 2, enc_f32(mx.z)); atomicMax(mp + 3, enc_f32(mx.w));
      if (lane == 0) atomicAdd(&counts[cur], j - i);

      i = j;
    }
  }

  // ---- completion ticket: last block to finish finalizes the output ----
  __syncthreads();
  __threadfence();  // all threads: make my atomics device-visible
  __syncthreads();
  if (threadIdx.x == 0) s_ticket = atomicAdd(done, 1u);
  __syncthreads();
  if (s_ticket != (unsigned)(nblocks - 1)) return;

  __threadfence();  // acquire side
  for (int t = threadIdx.x; t < SEGS * 2 * D; t += THREADS) {
    const int s = t / (2 * D);
    const int j = t % (2 * D);
    const int c = __hip_atomic_load(&counts[s], __ATOMIC_RELAXED,
                                    __HIP_MEMORY_SCOPE_AGENT);
    float v;
    if (j < D) {
      const float sv = __hip_atomic_load(&sums[s * D + j], __ATOMIC_RELAXED,
                                         __HIP_MEMORY_SCOPE_AGENT);
      v = (c > 0) ? sv / (float)c : 0.0f;
    } else {
      const unsigned k = __hip_atomic_load(&maxk[s * D + (j - D)],
                                           __ATOMIC_RELAXED,
                                           __HIP_MEMORY_SCOPE_AGENT);
      v = (c > 0) ? dec_f32(k) : 0.0f;
    }
    out[t] = v;
  }
}

extern "C" void kernel_launch(void* const* d_in, const int* in_sizes, int n_in,
                              void* d_out, int out_size, void* d_ws, size_t ws_size,
                              hipStream_t stream) {
  const float* feat = (const float*)d_in[0];
  const int*   idx  = (const int*)d_in[1];
  const int n = in_sizes[1];
  float* out = (float*)d_out;

  char* ws = (char*)d_ws;
  float*    sums   = (float*)ws;                        // 64 KiB
  unsigned* maxk   = (unsigned*)(ws + SEGS * D * 4);    // 64 KiB
  int*      counts = (int*)(ws + 2 * SEGS * D * 4);     // 256 B
  unsigned* done   = (unsigned*)(counts + SEGS);        // 4 B

  const size_t zero_bytes = 2 * (size_t)SEGS * D * 4 + SEGS * 4 + 4;
  hipMemsetAsync(ws, 0, zero_bytes, stream);

  const int nblocks = (n + RPB - 1) / RPB;
  fused_kernel<<<nblocks, THREADS, 0, stream>>>(feat, idx, sums, maxk, counts,
                                                done, out, n, nblocks);
}

// Round 8
// 220.810 us; speedup vs baseline: 2.8590x; 2.8590x over previous
//
#include <hip/hip_runtime.h>
#include <math.h>

#define D 256
#define SEGS 64
#define RPB 512      // rows per block
#define THREADS 256  // 4 waves; each wave streams RPB/4 = 128 contiguous rows
#define RPW (RPB / 4)

typedef float f32x4 __attribute__((ext_vector_type(4)));

// ---- ordered-uint encoding for float atomicMax ----
// key(f) monotone in f; key >= 0x007FFFFF for all finite floats,
// so the zero-initialized key acts as a -inf identity.
__device__ __forceinline__ unsigned enc_f32(float f) {
  unsigned u = __float_as_uint(f);
  return (u & 0x80000000u) ? ~u : (u | 0x80000000u);
}
__device__ __forceinline__ float dec_f32(unsigned k) {
  unsigned u = (k & 0x80000000u) ? (k ^ 0x80000000u) : ~k;
  return __uint_as_float(u);
}

// Self-contained aggregator: no init dependency. Each block stages its idx
// slice, detects idx width inline (sorted data's last int32 word is 63 for
// int32 data, or the 0 high-word of the last int64 element), scans runs in
// LDS, streams features with NT loads, and flushes one atomic set per run.
__global__ __launch_bounds__(THREADS, 4)
void agg_kernel(const float* __restrict__ feat, const int* __restrict__ idx,
                float* __restrict__ sums, unsigned* __restrict__ maxk,
                int* __restrict__ counts, int n) {
  __shared__ int s_idx[RPB];
  const int stride = (idx[(size_t)n - 1] == 0) ? 2 : 1;  // L2-hit scalar load
  const int r0 = blockIdx.x * RPB;
  const int rows = min(RPB, n - r0);

  for (int t = threadIdx.x; t < rows; t += THREADS)
    s_idx[t] = idx[(size_t)(r0 + t) * stride];
  __syncthreads();

  const int lane = threadIdx.x & 63;
  const int wave = threadIdx.x >> 6;
  int i = wave * RPW;
  const int re = min(i + RPW, rows);
  if (i >= re) return;

  const float* base = feat + (size_t)r0 * D + lane * 4;
  const int last = s_idx[re - 1];

  while (i < re) {
    const int cur = s_idx[i];
    int j;
    if (cur == last) {
      j = re;                       // fast path: run extends to range end
    } else {
      j = i + 1;                    // rare: <=63 boundary waves grid-wide
      while (s_idx[j] == cur) ++j;  // bounded: s_idx[re-1] != cur
    }

    f32x4 sum = {0.f, 0.f, 0.f, 0.f};
    f32x4 mx  = {-INFINITY, -INFINITY, -INFINITY, -INFINITY};
#pragma unroll 8
    for (int k = i; k < j; ++k) {
      const f32x4 v = __builtin_nontemporal_load(
          reinterpret_cast<const f32x4*>(base + (size_t)k * D));
      sum += v;
      mx.x = __builtin_fmaxf(mx.x, v.x);
      mx.y = __builtin_fmaxf(mx.y, v.y);
      mx.z = __builtin_fmaxf(mx.z, v.z);
      mx.w = __builtin_fmaxf(mx.w, v.w);
    }

    float* sp = sums + cur * D + lane * 4;
    atomicAdd(sp + 0, sum.x); atomicAdd(sp + 1, sum.y);
    atomicAdd(sp + 2, sum.z); atomicAdd(sp + 3, sum.w);
    unsigned* mp = maxk + cur * D + lane * 4;
    atomicMax(mp + 0, enc_f32(mx.x)); atomicMax(mp + 1, enc_f32(mx.y));
    atomicMax(mp + 2, enc_f32(mx.z)); atomicMax(mp + 3, enc_f32(mx.w));
    if (lane == 0) atomicAdd(&counts[cur], j - i);

    i = j;
  }
}

__global__ void finalize_kernel(const float* __restrict__ sums,
                                const unsigned* __restrict__ maxk,
                                const int* __restrict__ counts,
                                float* __restrict__ out) {
  int t = blockIdx.x * blockDim.x + threadIdx.x;
  if (t >= SEGS * 2 * D) return;
  int s = t / (2 * D);
  int j = t % (2 * D);
  int c = counts[s];
  float v;
  if (j < D)
    v = (c > 0) ? sums[s * D + j] / (float)c : 0.0f;
  else
    v = (c > 0) ? dec_f32(maxk[s * D + (j - D)]) : 0.0f;
  out[t] = v;
}

extern "C" void kernel_launch(void* const* d_in, const int* in_sizes, int n_in,
                              void* d_out, int out_size, void* d_ws, size_t ws_size,
                              hipStream_t stream) {
  const float* feat = (const float*)d_in[0];
  const int*   idx  = (const int*)d_in[1];
  const int n = in_sizes[1];
  float* out = (float*)d_out;

  char* ws = (char*)d_ws;
  float*    sums   = (float*)ws;                       // 64 KiB
  unsigned* maxk   = (unsigned*)(ws + SEGS * D * 4);   // 64 KiB
  int*      counts = (int*)(ws + 2 * SEGS * D * 4);    // 256 B

  const size_t zero_bytes = 2 * (size_t)SEGS * D * 4 + SEGS * 4;
  hipMemsetAsync(ws, 0, zero_bytes, stream);

  const int nblocks = (n + RPB - 1) / RPB;
  agg_kernel<<<nblocks, THREADS, 0, stream>>>(feat, idx, sums, maxk, counts, n);

  finalize_kernel<<<(SEGS * 2 * D + THREADS - 1) / THREADS, THREADS, 0, stream>>>(
      sums, maxk, counts, out);
}

// Round 9
// 217.887 us; speedup vs baseline: 2.8974x; 1.0134x over previous
//
#include <hip/hip_runtime.h>
#include <math.h>

#define D 256
#define SEGS 64
#define RPB 512      // rows per block
#define THREADS 256  // 4 waves; each wave streams RPB/4 = 128 contiguous rows

typedef float f32x4 __attribute__((ext_vector_type(4)));

// ---- ordered-uint encoding for float atomicMax ----
// key(f) monotone in f; key >= 0x007FFFFF for all finite floats,
// so the zero-initialized key acts as a -inf identity.
__device__ __forceinline__ unsigned enc_f32(float f) {
  unsigned u = __float_as_uint(f);
  return (u & 0x80000000u) ? ~u : (u | 0x80000000u);
}
__device__ __forceinline__ float dec_f32(unsigned k) {
  unsigned u = (k & 0x80000000u) ? (k ^ 0x80000000u) : ~k;
  return __uint_as_float(u);
}

// init: block s zeros segment s's ws slice and binary-searches bounds[s+1] =
// lower_bound(idx, s+1). idx width (int32 vs int64) detected from the last
// int32 word: sorted data ends in 63 (int32) or the 0 high-word (int64).
__global__ void init_kernel(const int* __restrict__ idx, int n,
                            float* __restrict__ sums,
                            unsigned* __restrict__ maxk,
                            int* __restrict__ bounds) {
  const int s = blockIdx.x;
  if (threadIdx.x < D) {
    sums[s * D + threadIdx.x] = 0.0f;
    maxk[s * D + threadIdx.x] = 0u;
  }
  if (threadIdx.x == 0) {
    const int stride = (idx[(size_t)n - 1] == 0) ? 2 : 1;
    const int v = s + 1;
    int lo = 0, hi = n;
    while (lo < hi) {
      int mid = (lo + hi) >> 1;
      if (idx[(size_t)mid * stride] < v) lo = mid + 1; else hi = mid;
    }
    bounds[s + 1] = lo;
    if (s == 0) bounds[0] = 0;
  }
}

__global__ __launch_bounds__(THREADS, 4)
void agg_kernel(const float* __restrict__ feat, const int* __restrict__ bounds,
                float* __restrict__ sums, unsigned* __restrict__ maxk, int n) {
  const int lane = threadIdx.x & 63;
  const int wave = threadIdx.x >> 6;
  int i = blockIdx.x * RPB + wave * (RPB / 4);
  const int re = min(i + (RPB / 4), n);
  if (i >= re) return;

  // b_end = bounds[lane+1] = end row of segment `lane` (one coalesced load).
  const int b_end = bounds[lane + 1];
  // segment of row i: number of segment-ends <= i (handles empties).
  int cur = (int)__popcll(__ballot(b_end <= i));

  const float* base = feat + lane * 4;

  while (true) {
    const int e = __shfl(b_end, cur);   // end of current segment
    const int j = min(re, e);           // invariant: j > i

    f32x4 sum = {0.f, 0.f, 0.f, 0.f};
    f32x4 mx  = {-INFINITY, -INFINITY, -INFINITY, -INFINITY};
#pragma unroll 8
    for (int k = i; k < j; ++k) {
      const f32x4 v = __builtin_nontemporal_load(
          reinterpret_cast<const f32x4*>(base + (size_t)k * D));
      sum += v;
      mx.x = __builtin_fmaxf(mx.x, v.x);
      mx.y = __builtin_fmaxf(mx.y, v.y);
      mx.z = __builtin_fmaxf(mx.z, v.z);
      mx.w = __builtin_fmaxf(mx.w, v.w);
    }

    float* sp = sums + cur * D + lane * 4;
    atomicAdd(sp + 0, sum.x); atomicAdd(sp + 1, sum.y);
    atomicAdd(sp + 2, sum.z); atomicAdd(sp + 3, sum.w);
    unsigned* mp = maxk + cur * D + lane * 4;
    atomicMax(mp + 0, enc_f32(mx.x)); atomicMax(mp + 1, enc_f32(mx.y));
    atomicMax(mp + 2, enc_f32(mx.z)); atomicMax(mp + 3, enc_f32(mx.w));

    if (j >= re) break;
    i = j;
    do { ++cur; } while (__shfl(b_end, cur) <= i);  // skip empty segments
  }
}

__global__ void finalize_kernel(const float* __restrict__ sums,
                                const unsigned* __restrict__ maxk,
                                const int* __restrict__ bounds,
                                float* __restrict__ out) {
  int t = blockIdx.x * blockDim.x + threadIdx.x;
  if (t >= SEGS * 2 * D) return;
  int s = t / (2 * D);
  int j = t % (2 * D);
  int c = bounds[s + 1] - bounds[s];
  float v;
  if (j < D)
    v = (c > 0) ? sums[s * D + j] / (float)c : 0.0f;
  else
    v = (c > 0) ? dec_f32(maxk[s * D + (j - D)]) : 0.0f;
  out[t] = v;
}

extern "C" void kernel_launch(void* const* d_in, const int* in_sizes, int n_in,
                              void* d_out, int out_size, void* d_ws, size_t ws_size,
                              hipStream_t stream) {
  const float* feat = (const float*)d_in[0];
  const int*   idx  = (const int*)d_in[1];
  const int n = in_sizes[1];
  float* out = (float*)d_out;

  char* ws = (char*)d_ws;
  float*    sums   = (float*)ws;                       // 64 KiB
  unsigned* maxk   = (unsigned*)(ws + SEGS * D * 4);   // 64 KiB
  int*      bounds = (int*)(ws + 2 * SEGS * D * 4);    // 65 ints

  init_kernel<<<SEGS, THREADS, 0, stream>>>(idx, n, sums, maxk, bounds);

  const int nblocks = (n + RPB - 1) / RPB;
  agg_kernel<<<nblocks, THREADS, 0, stream>>>(feat, bounds, sums, maxk, n);

  finalize_kernel<<<(SEGS * 2 * D + THREADS - 1) / THREADS, THREADS, 0, stream>>>(
      sums, maxk, bounds, out);
}